// Round 1
// baseline (235.724 us; speedup 1.0000x reference)
//
#include <hip/hip_runtime.h>
#include <stdint.h>

typedef unsigned short u16;
typedef __attribute__((ext_vector_type(8))) __bf16 bf16x8;
typedef __attribute__((ext_vector_type(4))) float f32x4;

constexpr int B_ = 8, CH = 512, T = 1024, NH = 8, HD = 64, BAND = 256;

__device__ inline u16 f2b(float f) {
  union { float f; uint32_t u; } v; v.f = f;
  uint32_t r = (v.u + 0x7fffu + ((v.u >> 16) & 1u)) >> 16;
  return (u16)r;
}

__device__ inline f32x4 mfma16(bf16x8 a, bf16x8 b, f32x4 c) {
  return __builtin_amdgcn_mfma_f32_16x16x32_bf16(a, b, c, 0, 0, 0);
}

// ---- weights fp32 -> bf16, 4x [512][512] row-major (k=c contiguous) ----
__global__ __launch_bounds__(256) void cvt_w(const float* __restrict__ wq, const float* __restrict__ wk,
                                             const float* __restrict__ wv, const float* __restrict__ wo,
                                             u16* __restrict__ out) {
  int idx = blockIdx.x * 256 + threadIdx.x;      // 131072 threads, 8 elems each
  int w = idx >> 15;
  const float* src = (w == 0) ? wq : (w == 1) ? wk : (w == 2) ? wv : wo;
  int e = (idx & 32767) * 8;
  f32x4 a = *(const f32x4*)(src + e);
  f32x4 b = *(const f32x4*)(src + e + 4);
  union { u16 h[8]; bf16x8 v; } r;
  r.h[0] = f2b(a[0]); r.h[1] = f2b(a[1]); r.h[2] = f2b(a[2]); r.h[3] = f2b(a[3]);
  r.h[4] = f2b(b[0]); r.h[5] = f2b(b[1]); r.h[6] = f2b(b[2]); r.h[7] = f2b(b[3]);
  *(bf16x8*)(out + (w << 18) + e) = r.v;
}

// ---- x,c [B][CH][T] fp32 -> xT,cT [B][T][CH] bf16 (32x32 LDS tiles) ----
__global__ __launch_bounds__(256) void tr_cvt(const float* __restrict__ x, const float* __restrict__ c,
                                              u16* __restrict__ xT, u16* __restrict__ cT) {
  __shared__ float tile[32][33];
  int z = blockIdx.z;
  const float* src = (z < B_) ? x : c;
  u16* dst = (z < B_) ? xT : cT;
  int b = (z < B_) ? z : z - B_;
  int t0 = blockIdx.x * 32, c0 = blockIdx.y * 32;
  int tx = threadIdx.x & 31, ty = threadIdx.x >> 5;
#pragma unroll
  for (int k = 0; k < 4; k++)
    tile[ty + 8 * k][tx] = src[(long)(b * CH + c0 + ty + 8 * k) * T + t0 + tx];
  __syncthreads();
#pragma unroll
  for (int k = 0; k < 4; k++)
    dst[(long)(b * T + t0 + ty + 8 * k) * CH + c0 + tx] = f2b(tile[tx][ty + 8 * k]);
}

// ---- generic NT GEMM: C[M][N] = A[M][K] * B[N][K]^T + bias ----
// 64x64 tile / block (4 waves in 2x2), BK=64, bf16 MFMA 16x16x32, fp32 acc.
template <typename OT, bool BROW>
__global__ __launch_bounds__(256) void gemm_nt(const u16* __restrict__ A, long sA,
                                               const u16* __restrict__ Bm, long sB,
                                               OT* __restrict__ C, long sC,
                                               const float* __restrict__ bias,
                                               int lda, int ldb, int ldc, int K) {
  __shared__ u16 lA[64][72], lB[64][72];   // +8 pad: <=2-way bank alias (free)
  int m0 = blockIdx.y * 64, n0 = blockIdx.x * 64;
  int lane = threadIdx.x & 63, wave = threadIdx.x >> 6;
  int cl = lane & 15, quad = lane >> 4;
  int wm = wave >> 1, wn = wave & 1;
  const u16* Ab = A + blockIdx.z * sA;
  const u16* Bb = Bm + blockIdx.z * sB;
  f32x4 acc[2][2] = {};
  int r0 = threadIdx.x >> 3, c8 = (threadIdx.x & 7) * 8;
  for (int k0 = 0; k0 < K; k0 += 64) {
    __syncthreads();
    *(bf16x8*)&lA[r0][c8]      = *(const bf16x8*)(Ab + (long)(m0 + r0) * lda + k0 + c8);
    *(bf16x8*)&lA[r0 + 32][c8] = *(const bf16x8*)(Ab + (long)(m0 + r0 + 32) * lda + k0 + c8);
    *(bf16x8*)&lB[r0][c8]      = *(const bf16x8*)(Bb + (long)(n0 + r0) * ldb + k0 + c8);
    *(bf16x8*)&lB[r0 + 32][c8] = *(const bf16x8*)(Bb + (long)(n0 + r0 + 32) * ldb + k0 + c8);
    __syncthreads();
#pragma unroll
    for (int ks = 0; ks < 2; ks++) {
      bf16x8 a0 = *(bf16x8*)&lA[wm * 32 + cl][ks * 32 + quad * 8];
      bf16x8 a1 = *(bf16x8*)&lA[wm * 32 + 16 + cl][ks * 32 + quad * 8];
      bf16x8 b0 = *(bf16x8*)&lB[wn * 32 + cl][ks * 32 + quad * 8];
      bf16x8 b1 = *(bf16x8*)&lB[wn * 32 + 16 + cl][ks * 32 + quad * 8];
      acc[0][0] = mfma16(a0, b0, acc[0][0]);
      acc[0][1] = mfma16(a0, b1, acc[0][1]);
      acc[1][0] = mfma16(a1, b0, acc[1][0]);
      acc[1][1] = mfma16(a1, b1, acc[1][1]);
    }
  }
  OT* Cb = C + blockIdx.z * sC;
#pragma unroll
  for (int mg = 0; mg < 2; mg++)
#pragma unroll
    for (int ng = 0; ng < 2; ng++)
#pragma unroll
      for (int r = 0; r < 4; r++) {
        int row = m0 + wm * 32 + mg * 16 + quad * 4 + r;   // D row = quad*4+reg
        int col = n0 + wn * 32 + ng * 16 + cl;             // D col = lane&15
        float v = acc[mg][ng][r] + (BROW ? bias[row] : bias[col]);
        if constexpr (sizeof(OT) == 2) Cb[(long)row * ldc + col] = f2b(v);
        else Cb[(long)row * ldc + col] = v;
      }
}

// ---- banded flash attention: 1 wave per 16 query rows ----
// Q,K: [B][T][CH] bf16 (d contiguous); V: [B][CH][T] bf16 (s contiguous)
// AO out: [B][T][CH] bf16. attn_mask is constant all-ones -> identity, skipped.
__global__ __launch_bounds__(256) void attn(const u16* __restrict__ Q, const u16* __restrict__ Kt,
                                            const u16* __restrict__ V, u16* __restrict__ AO) {
  __shared__ u16 pb[4][16][40];  // per-wave P bounce, C-layout -> A-layout
  int lane = threadIdx.x & 63, wave = threadIdx.x >> 6;
  int cl = lane & 15, quad = lane >> 4;
  int bh = blockIdx.x >> 4;
  int b = bh >> 3, h = bh & 7;
  int tq0 = (blockIdx.x & 15) * 64 + wave * 16;
  const u16* qb = Q + ((long)(b * T + tq0 + cl) * CH) + h * HD;
  bf16x8 qf0 = *(const bf16x8*)(qb + quad * 8);         // d 0..31
  bf16x8 qf1 = *(const bf16x8*)(qb + 32 + quad * 8);    // d 32..63
  f32x4 acc[4] = {};
  float m_i[4], l_i[4];
#pragma unroll
  for (int r = 0; r < 4; r++) { m_i[r] = -1e4f; l_i[r] = 0.f; }  // ref row-max floor is -1e4
  int s_lo = tq0 - BAND; if (s_lo < 0) s_lo = 0; s_lo &= ~31;    // 32-aligned, stays in [0,T)
  int s_hi = tq0 + 16 + BAND; if (s_hi > T) s_hi = T;
  for (int j0 = s_lo; j0 < s_hi; j0 += 32) {
    const u16* kb = Kt + ((long)(b * T + j0 + cl) * CH) + h * HD;
    bf16x8 k00 = *(const bf16x8*)(kb + quad * 8);
    bf16x8 k01 = *(const bf16x8*)(kb + 32 + quad * 8);
    bf16x8 k10 = *(const bf16x8*)(kb + 16 * CH + quad * 8);
    bf16x8 k11 = *(const bf16x8*)(kb + 16 * CH + 32 + quad * 8);
    f32x4 z = {0.f, 0.f, 0.f, 0.f};
    f32x4 s0 = mfma16(qf1, k01, mfma16(qf0, k00, z));   // cols j0..j0+15
    f32x4 s1 = mfma16(qf1, k11, mfma16(qf0, k10, z));   // cols j0+16..j0+31
    float al[4];
#pragma unroll
    for (int r = 0; r < 4; r++) {
      int i = tq0 + quad * 4 + r;
      int ja = j0 + cl, jb2 = j0 + 16 + cl;
      int da = i > ja ? i - ja : ja - i;
      int db = i > jb2 ? i - jb2 : jb2 - i;
      // scale 1/8 (exact pow2), proximal bias -log1p(|i-j|); out-of-band -> -inf (exp->0,
      // matches ref where exp(-1e4 - m) underflows to exactly 0 in fp32)
      float sa = (da <= BAND) ? s0[r] * 0.125f - __logf(1.f + (float)da) : -__builtin_inff();
      float sb = (db <= BAND) ? s1[r] * 0.125f - __logf(1.f + (float)db) : -__builtin_inff();
      float rm = fmaxf(sa, sb);
      rm = fmaxf(rm, __shfl_xor(rm, 1));
      rm = fmaxf(rm, __shfl_xor(rm, 2));
      rm = fmaxf(rm, __shfl_xor(rm, 4));
      rm = fmaxf(rm, __shfl_xor(rm, 8));
      float mn = fmaxf(m_i[r], rm);
      al[r] = __expf(m_i[r] - mn);
      m_i[r] = mn;
      float ea = __expf(sa - mn), eb = __expf(sb - mn);
      float rs = ea + eb;
      rs += __shfl_xor(rs, 1);
      rs += __shfl_xor(rs, 2);
      rs += __shfl_xor(rs, 4);
      rs += __shfl_xor(rs, 8);
      l_i[r] = l_i[r] * al[r] + rs;
      pb[wave][quad * 4 + r][cl] = f2b(ea);
      pb[wave][quad * 4 + r][16 + cl] = f2b(eb);
    }
#pragma unroll
    for (int dg = 0; dg < 4; dg++) {
      f32x4 t = acc[dg];
      t[0] *= al[0]; t[1] *= al[1]; t[2] *= al[2]; t[3] *= al[3];
      acc[dg] = t;
    }
    // P: C-layout -> A-operand layout via LDS (wave-local, no barrier needed)
    bf16x8 pf = *(bf16x8*)&pb[wave][cl][quad * 8];
#pragma unroll
    for (int dg = 0; dg < 4; dg++) {
      const u16* vb = V + ((long)(b * CH + h * HD + dg * 16 + cl) * T) + j0 + quad * 8;
      acc[dg] = mfma16(pf, *(const bf16x8*)vb, acc[dg]);
    }
  }
  float inv[4];
#pragma unroll
  for (int r = 0; r < 4; r++) inv[r] = 1.f / l_i[r];
#pragma unroll
  for (int dg = 0; dg < 4; dg++)
#pragma unroll
    for (int r = 0; r < 4; r++)
      AO[((long)(b * T + tq0 + quad * 4 + r) * CH) + h * HD + dg * 16 + cl] = f2b(acc[dg][r] * inv[r]);
}

extern "C" void kernel_launch(void* const* d_in, const int* in_sizes, int n_in,
                              void* d_out, int out_size, void* d_ws, size_t ws_size,
                              hipStream_t stream) {
  const float* x  = (const float*)d_in[0];
  const float* c  = (const float*)d_in[1];
  // d_in[2] = attn_mask: constant all-ones -> masked_fill is identity, skipped
  const float* Wq = (const float*)d_in[3];
  const float* bq = (const float*)d_in[4];
  const float* Wk = (const float*)d_in[5];
  const float* bk = (const float*)d_in[6];
  const float* Wv = (const float*)d_in[7];
  const float* bv = (const float*)d_in[8];
  const float* Wo = (const float*)d_in[9];
  const float* bo = (const float*)d_in[10];
  float* out = (float*)d_out;

  const long NT = (long)B_ * T * CH;  // 4,194,304 elems
  u16* Wb = (u16*)d_ws;               // 4 x 512x512 bf16
  u16* xT = Wb + 4 * 262144;
  u16* cT = xT + NT;
  u16* Qb = cT + NT;
  u16* Kb = Qb + NT;
  u16* Vb = Kb + NT;
  u16* AO = xT;                       // xT dead after Q-GEMM; reuse (total ws: 42 MB)

  cvt_w<<<dim3(512), dim3(256), 0, stream>>>(Wq, Wk, Wv, Wo, Wb);
  tr_cvt<<<dim3(32, 16, 16), dim3(256), 0, stream>>>(x, c, xT, cT);
  // Q = xT * Wq^T -> [B][T][CH]
  gemm_nt<u16, false><<<dim3(8, 16, 8), dim3(256), 0, stream>>>(xT, (long)T * CH, Wb, 0,
                                                                Qb, (long)T * CH, bq, CH, CH, CH, CH);
  // K = cT * Wk^T -> [B][T][CH]
  gemm_nt<u16, false><<<dim3(8, 16, 8), dim3(256), 0, stream>>>(cT, (long)T * CH, Wb + 262144, 0,
                                                                Kb, (long)T * CH, bk, CH, CH, CH, CH);
  // V = Wv * cT^T -> [B][CH][T] (s-contiguous for PV B-operand)
  gemm_nt<u16, true><<<dim3(16, 8, 8), dim3(256), 0, stream>>>(Wb + 2 * 262144, 0, cT, (long)T * CH,
                                                               Vb, (long)CH * T, bv, CH, CH, T, CH);
  attn<<<dim3(1024), dim3(256), 0, stream>>>(Qb, Kb, Vb, AO);
  // out = Wo * AO^T -> [B][CH][T] fp32
  gemm_nt<float, true><<<dim3(16, 8, 8), dim3(256), 0, stream>>>(Wb + 3 * 262144, 0, AO, (long)T * CH,
                                                                 out, (long)CH * T, bo, CH, CH, T, CH);
}

// Round 2
// 210.960 us; speedup vs baseline: 1.1174x; 1.1174x over previous
//
#include <hip/hip_runtime.h>
#include <stdint.h>

typedef unsigned short u16;
typedef __attribute__((ext_vector_type(8))) __bf16 bf16x8;
typedef __attribute__((ext_vector_type(4))) float f32x4;

constexpr int B_ = 8, CH = 512, T = 1024, NH = 8, HD = 64, BAND = 256;

__device__ inline u16 f2b(float f) {
  union { float f; uint32_t u; } v; v.f = f;
  uint32_t r = (v.u + 0x7fffu + ((v.u >> 16) & 1u)) >> 16;
  return (u16)r;
}

__device__ inline f32x4 mfma16(bf16x8 a, bf16x8 b, f32x4 c) {
  return __builtin_amdgcn_mfma_f32_16x16x32_bf16(a, b, c, 0, 0, 0);
}

// async global->LDS, 16B per lane; lds dest = wave-uniform base + lane*16
__device__ __forceinline__ void gld16(const void* g, void* l) {
  __builtin_amdgcn_global_load_lds((__attribute__((address_space(1))) void*)(g),
                                   (__attribute__((address_space(3))) void*)(l),
                                   16, 0, 0);
}

// ---- weights fp32 -> bf16, 4x [512][512] row-major (k=c contiguous) ----
__global__ __launch_bounds__(256) void cvt_w(const float* __restrict__ wq, const float* __restrict__ wk,
                                             const float* __restrict__ wv, const float* __restrict__ wo,
                                             u16* __restrict__ out) {
  int idx = blockIdx.x * 256 + threadIdx.x;
  int w = idx >> 15;
  const float* src = (w == 0) ? wq : (w == 1) ? wk : (w == 2) ? wv : wo;
  int e = (idx & 32767) * 8;
  f32x4 a = *(const f32x4*)(src + e);
  f32x4 b = *(const f32x4*)(src + e + 4);
  union { u16 h[8]; bf16x8 v; } r;
  r.h[0] = f2b(a[0]); r.h[1] = f2b(a[1]); r.h[2] = f2b(a[2]); r.h[3] = f2b(a[3]);
  r.h[4] = f2b(b[0]); r.h[5] = f2b(b[1]); r.h[6] = f2b(b[2]); r.h[7] = f2b(b[3]);
  *(bf16x8*)(out + (w << 18) + e) = r.v;
}

// ---- x,c [B][CH][T] fp32 -> xT,cT [B][T][CH] bf16 ----
__global__ __launch_bounds__(256) void tr_cvt(const float* __restrict__ x, const float* __restrict__ c,
                                              u16* __restrict__ xT, u16* __restrict__ cT) {
  __shared__ float tile[32][33];
  int z = blockIdx.z;
  const float* src = (z < B_) ? x : c;
  u16* dst = (z < B_) ? xT : cT;
  int b = (z < B_) ? z : z - B_;
  int t0 = blockIdx.x * 32, c0 = blockIdx.y * 32;
  int tx = threadIdx.x & 31, ty = threadIdx.x >> 5;
#pragma unroll
  for (int k = 0; k < 4; k++)
    tile[ty + 8 * k][tx] = src[(long)(b * CH + c0 + ty + 8 * k) * T + t0 + tx];
  __syncthreads();
#pragma unroll
  for (int k = 0; k < 4; k++)
    dst[(long)(b * T + t0 + ty + 8 * k) * CH + c0 + tx] = f2b(tile[tx][ty + 8 * k]);
}

// ---- 128x128-tile NT GEMM: C[M][N] = A[M][K]*B[N][K]^T + bias ----
// BK=64, 4 waves (2x2), 4x4 16x16 acc tiles/wave, global_load_lds staging.
// LDS layout XOR-swizzled: A elem (row, 16B-chunk g) stored at chunk g^(row&7)
// -> b128 fragment reads are conflict-free; swizzle applied on source address
// (LDS dest of global_load_lds is fixed wave-uniform+lane*16).
// Dual problem sets selected by blockIdx.z >= zsplit (merges Q & K projections).
template <typename OT, bool BROW>
__global__ __launch_bounds__(256) void gemm128(const u16* __restrict__ A1, const u16* __restrict__ A2, long sA,
                                               const u16* __restrict__ B1, const u16* __restrict__ B2, long sB,
                                               OT* __restrict__ C1, OT* __restrict__ C2, long sC,
                                               const float* __restrict__ bi1, const float* __restrict__ bi2,
                                               int zsplit, int lda, int ldb, int ldc, int K) {
  __shared__ u16 sm[2 * 128 * 64];           // 32 KB: A tile | B tile
  u16* smA = sm;
  u16* smB = sm + 128 * 64;
  int z = blockIdx.z;
  bool sec = z >= zsplit;
  int zz = sec ? z - zsplit : z;
  const u16* Ab = (sec ? A2 : A1) + (long)zz * sA;
  const u16* Bb = (sec ? B2 : B1) + (long)zz * sB;
  OT* Cb = (sec ? C2 : C1) + (long)zz * sC;
  const float* bi = sec ? bi2 : bi1;
  int m0 = blockIdx.y * 128, n0 = blockIdx.x * 128;
  int t = threadIdx.x, lane = t & 63, wave = t >> 6;
  int cl = lane & 15, quad = lane >> 4;
  int wm = wave >> 1, wn = wave & 1;
  int rr = t >> 3, gs = t & 7;               // staging: row-in-32-group, stored chunk
  f32x4 acc[4][4] = {};
  for (int k0 = 0; k0 < K; k0 += 64) {
    __syncthreads();
#pragma unroll
    for (int j = 0; j < 4; j++) {
      int R = j * 32 + rr;
      int gc = (gs ^ (R & 7)) << 3;          // swizzled source k-offset
      gld16(Ab + (long)(m0 + R) * lda + k0 + gc, (char*)smA + j * 4096 + wave * 1024);
      gld16(Bb + (long)(n0 + R) * ldb + k0 + gc, (char*)smB + j * 4096 + wave * 1024);
    }
    __syncthreads();                          // drains vmcnt (global_load_lds)
#pragma unroll
    for (int ks = 0; ks < 2; ks++) {
      int g2 = ((ks << 2) | quad) ^ (cl & 7);
      bf16x8 af[4], bb[4];
#pragma unroll
      for (int i = 0; i < 4; i++) {
        af[i] = *(const bf16x8*)&smA[(wm * 64 + i * 16 + cl) * 64 + g2 * 8];
        bb[i] = *(const bf16x8*)&smB[(wn * 64 + i * 16 + cl) * 64 + g2 * 8];
      }
#pragma unroll
      for (int mi = 0; mi < 4; mi++)
#pragma unroll
        for (int ni = 0; ni < 4; ni++)
          acc[mi][ni] = mfma16(af[mi], bb[ni], acc[mi][ni]);
    }
  }
#pragma unroll
  for (int mi = 0; mi < 4; mi++) {
    int row = m0 + wm * 64 + mi * 16 + quad * 4;
#pragma unroll
    for (int ni = 0; ni < 4; ni++) {
      int col = n0 + wn * 64 + ni * 16 + cl;
#pragma unroll
      for (int r = 0; r < 4; r++) {
        float v = acc[mi][ni][r] + (BROW ? bi[row + r] : bi[col]);
        if constexpr (sizeof(OT) == 2) Cb[(long)(row + r) * ldc + col] = f2b(v);
        else Cb[(long)(row + r) * ldc + col] = v;
      }
    }
  }
}

// ---- banded attention, no online softmax (scores bounded -> raw exp safe) ----
// Q,K: [B][T][CH] bf16; V: [B][CH][T] bf16; AO: [B][T][CH] bf16.
// K rows interleaved (lane cl holds rows j0+2cl, j0+2cl+1) so each lane's two
// P values are j-adjacent -> one packed ds_write_b32. l accumulated per-lane,
// reduced once at the end. Out-of-band -> exact 0 (matches ref underflow).
__global__ __launch_bounds__(256) void attn(const u16* __restrict__ Q, const u16* __restrict__ Kt,
                                            const u16* __restrict__ V, u16* __restrict__ AO) {
  __shared__ u16 pb[4][16][40];  // per-wave P bounce; row stride 80B: writes/reads <=2-way (free)
  int lane = threadIdx.x & 63, wave = threadIdx.x >> 6;
  int cl = lane & 15, quad = lane >> 4;
  int bh = blockIdx.x >> 4;
  int b = bh >> 3, h = bh & 7;
  int tq0 = (blockIdx.x & 15) * 64 + wave * 16;
  const u16* qb = Q + ((long)(b * T + tq0 + cl) * CH) + h * HD;
  bf16x8 qf0 = *(const bf16x8*)(qb + quad * 8);
  bf16x8 qf1 = *(const bf16x8*)(qb + 32 + quad * 8);
  f32x4 acc[4] = {};
  float lr[4] = {0.f, 0.f, 0.f, 0.f};
  float fir[4];
#pragma unroll
  for (int r = 0; r < 4; r++) fir[r] = (float)(tq0 + quad * 4 + r);
  int s_lo = tq0 - BAND; if (s_lo < 0) s_lo = 0; s_lo &= ~31;
  int s_hi = tq0 + 16 + BAND; if (s_hi > T) s_hi = T;
  float je = (float)(s_lo + 2 * cl);
  for (int j0 = s_lo; j0 < s_hi; j0 += 32, je += 32.f) {
    const u16* kb = Kt + ((long)(b * T + j0 + 2 * cl) * CH) + h * HD;
    bf16x8 k00 = *(const bf16x8*)(kb + quad * 8);            // row j0+2cl (even cols)
    bf16x8 k01 = *(const bf16x8*)(kb + 32 + quad * 8);
    bf16x8 k10 = *(const bf16x8*)(kb + CH + quad * 8);       // row j0+2cl+1 (odd cols)
    bf16x8 k11 = *(const bf16x8*)(kb + CH + 32 + quad * 8);
    f32x4 z = {0.f, 0.f, 0.f, 0.f};
    f32x4 s0 = mfma16(qf1, k01, mfma16(qf0, k00, z));        // P cols j0+2n
    f32x4 s1 = mfma16(qf1, k11, mfma16(qf0, k10, z));        // P cols j0+2n+1
#pragma unroll
    for (int r = 0; r < 4; r++) {
      float de = fabsf(fir[r] - je);
      float dd = fabsf(fir[r] - je - 1.f);
      // p = exp(qk/8) / (1+d)  ==  exp(qk/8 - log1p(d)); softmax is shift-invariant
      float pe = __expf(s0[r] * 0.125f) * __builtin_amdgcn_rcpf(1.f + de);
      float po = __expf(s1[r] * 0.125f) * __builtin_amdgcn_rcpf(1.f + dd);
      pe = (de <= 256.f) ? pe : 0.f;
      po = (dd <= 256.f) ? po : 0.f;
      lr[r] += pe + po;
      uint32_t ue, uo;
      { union { float f; uint32_t u; } cv; cv.f = pe; ue = cv.u; cv.f = po; uo = cv.u; }
      uint32_t pk = ((uo + 0x8000u) & 0xffff0000u) | ((ue + 0x8000u) >> 16);  // [odd|even] bf16 rn
      *(uint32_t*)&pb[wave][quad * 4 + r][2 * cl] = pk;
    }
    bf16x8 pf = *(bf16x8*)&pb[wave][cl][quad * 8];   // A-operand layout, wave-local
#pragma unroll
    for (int dg = 0; dg < 4; dg++) {
      const u16* vb = V + ((long)(b * CH + h * HD + dg * 16 + cl) * T) + j0 + quad * 8;
      acc[dg] = mfma16(pf, *(const bf16x8*)vb, acc[dg]);
    }
  }
  float inv[4];
#pragma unroll
  for (int r = 0; r < 4; r++) {
    float s = lr[r];
    s += __shfl_xor(s, 1); s += __shfl_xor(s, 2);
    s += __shfl_xor(s, 4); s += __shfl_xor(s, 8);   // sum over the 16 cl lanes
    inv[r] = __builtin_amdgcn_rcpf(s);
  }
#pragma unroll
  for (int dg = 0; dg < 4; dg++)
#pragma unroll
    for (int r = 0; r < 4; r++)
      AO[((long)(b * T + tq0 + quad * 4 + r) * CH) + h * HD + dg * 16 + cl] = f2b(acc[dg][r] * inv[r]);
}

extern "C" void kernel_launch(void* const* d_in, const int* in_sizes, int n_in,
                              void* d_out, int out_size, void* d_ws, size_t ws_size,
                              hipStream_t stream) {
  const float* x  = (const float*)d_in[0];
  const float* c  = (const float*)d_in[1];
  // d_in[2] = attn_mask: constant all-ones -> identity, skipped
  const float* Wq = (const float*)d_in[3];
  const float* bq = (const float*)d_in[4];
  const float* Wk = (const float*)d_in[5];
  const float* bk = (const float*)d_in[6];
  const float* Wv = (const float*)d_in[7];
  const float* bv = (const float*)d_in[8];
  const float* Wo = (const float*)d_in[9];
  const float* bo = (const float*)d_in[10];
  float* out = (float*)d_out;

  const long NT = (long)B_ * T * CH;
  u16* Wb = (u16*)d_ws;               // 4 x 512x512 bf16
  u16* xT = Wb + 4 * 262144;
  u16* cT = xT + NT;
  u16* Qb = cT + NT;
  u16* Kb = Qb + NT;
  u16* Vb = Kb + NT;
  u16* AO = xT;                       // xT dead after QK-GEMM; reuse

  cvt_w<<<dim3(512), dim3(256), 0, stream>>>(Wq, Wk, Wv, Wo, Wb);
  tr_cvt<<<dim3(32, 16, 16), dim3(256), 0, stream>>>(x, c, xT, cT);
  // merged Q (z<8) + K (z>=8) projections: [B][T][CH] = xT/cT * W^T, 512 blocks
  gemm128<u16, false><<<dim3(4, 8, 16), dim3(256), 0, stream>>>(
      xT, cT, (long)T * CH, Wb, Wb + 262144, 0,
      Qb, Kb, (long)T * CH, bq, bk, 8, CH, CH, CH, CH);
  // V = Wv * cT^T -> [B][CH][T] (s-contiguous for PV B-operand)
  gemm128<u16, true><<<dim3(8, 4, 8), dim3(256), 0, stream>>>(
      Wb + 2 * 262144, Wb + 2 * 262144, 0, cT, cT, (long)T * CH,
      Vb, Vb, (long)CH * T, bv, bv, 8, CH, CH, T, CH);
  attn<<<dim3(1024), dim3(256), 0, stream>>>(Qb, Kb, Vb, AO);
  // out = Wo * AO^T -> [B][CH][T] fp32
  gemm128<float, true><<<dim3(8, 4, 8), dim3(256), 0, stream>>>(
      Wb + 3 * 262144, Wb + 3 * 262144, 0, AO, AO, (long)T * CH,
      out, out, (long)CH * T, bo, bo, 8, CH, CH, T, CH);
}

// Round 4
// 189.060 us; speedup vs baseline: 1.2468x; 1.1158x over previous
//
#include <hip/hip_runtime.h>
#include <stdint.h>

typedef unsigned short u16;
typedef __attribute__((ext_vector_type(8))) __bf16 bf16x8;
typedef __attribute__((ext_vector_type(4))) float f32x4;

constexpr int B_ = 8, CH = 512, T = 1024, NH = 8, HD = 64, BAND = 256;

__device__ inline u16 f2b(float f) {
  union { float f; uint32_t u; } v; v.f = f;
  uint32_t r = (v.u + 0x7fffu + ((v.u >> 16) & 1u)) >> 16;
  return (u16)r;
}

__device__ inline f32x4 mfma16(bf16x8 a, bf16x8 b, f32x4 c) {
  return __builtin_amdgcn_mfma_f32_16x16x32_bf16(a, b, c, 0, 0, 0);
}

__device__ __forceinline__ void gld16(const void* g, void* l) {
  __builtin_amdgcn_global_load_lds((__attribute__((address_space(1))) void*)(g),
                                   (__attribute__((address_space(3))) void*)(l),
                                   16, 0, 0);
}

// 2^x via v_exp_f32 directly (NOT __exp2f: glibc math.h macro clash on this toolchain)
__device__ __forceinline__ float exp2_hw(float x) { return __builtin_amdgcn_exp2f(x); }

// ---- weights fp32 -> bf16, 4x [512][512] row-major ----
__global__ __launch_bounds__(256) void cvt_w(const float* __restrict__ wq, const float* __restrict__ wk,
                                             const float* __restrict__ wv, const float* __restrict__ wo,
                                             u16* __restrict__ out) {
  int idx = blockIdx.x * 256 + threadIdx.x;
  int w = idx >> 15;
  const float* src = (w == 0) ? wq : (w == 1) ? wk : (w == 2) ? wv : wo;
  int e = (idx & 32767) * 8;
  f32x4 a = *(const f32x4*)(src + e);
  f32x4 b = *(const f32x4*)(src + e + 4);
  union { u16 h[8]; bf16x8 v; } r;
  r.h[0] = f2b(a[0]); r.h[1] = f2b(a[1]); r.h[2] = f2b(a[2]); r.h[3] = f2b(a[3]);
  r.h[4] = f2b(b[0]); r.h[5] = f2b(b[1]); r.h[6] = f2b(b[2]); r.h[7] = f2b(b[3]);
  *(bf16x8*)(out + (w << 18) + e) = r.v;
}

// ---- x,c [B][CH][T] fp32 -> xT,cT [B][T][CH] bf16 ----
__global__ __launch_bounds__(256) void tr_cvt(const float* __restrict__ x, const float* __restrict__ c,
                                              u16* __restrict__ xT, u16* __restrict__ cT) {
  __shared__ float tile[32][33];
  int z = blockIdx.z;
  const float* src = (z < B_) ? x : c;
  u16* dst = (z < B_) ? xT : cT;
  int b = (z < B_) ? z : z - B_;
  int t0 = blockIdx.x * 32, c0 = blockIdx.y * 32;
  int tx = threadIdx.x & 31, ty = threadIdx.x >> 5;
#pragma unroll
  for (int k = 0; k < 4; k++)
    tile[ty + 8 * k][tx] = src[(long)(b * CH + c0 + ty + 8 * k) * T + t0 + tx];
  __syncthreads();
#pragma unroll
  for (int k = 0; k < 4; k++)
    dst[(long)(b * T + t0 + ty + 8 * k) * CH + c0 + tx] = f2b(tile[tx][ty + 8 * k]);
}

// ---- shared GEMM core: 128 x TN tile, BK=64, 4 waves, gld16 staging ----
// LDS chunk-swizzle: elem (row, 16B-chunk g) stored at chunk g^(row&7).
template <int TN, typename OT>
__device__ __forceinline__ void gemm_core(const u16* __restrict__ Ab, int lda,
                                          const u16* __restrict__ Bb, int ldb,
                                          OT* __restrict__ Cb, int ldc,
                                          const float* __restrict__ bi, bool brow,
                                          int m0, int n0, int K, u16* smA, u16* smB) {
  int t = threadIdx.x, lane = t & 63, wave = t >> 6;
  int cl = lane & 15, quad = lane >> 4;
  int wm = wave >> 1, wn = wave & 1;
  int rr = t >> 3, gs = t & 7;
  constexpr int NW = TN / 32;                 // acc cols per wave
  f32x4 acc[4][NW] = {};
  for (int k0 = 0; k0 < K; k0 += 64) {
    __syncthreads();
#pragma unroll
    for (int j = 0; j < 4; j++) {
      int R = j * 32 + rr;
      int gc = (gs ^ (R & 7)) << 3;
      gld16(Ab + (long)(m0 + R) * lda + k0 + gc, (char*)smA + j * 4096 + wave * 1024);
      if (j < TN / 32)
        gld16(Bb + (long)(n0 + R) * ldb + k0 + gc, (char*)smB + j * 4096 + wave * 1024);
    }
    __syncthreads();
#pragma unroll
    for (int ks = 0; ks < 2; ks++) {
      int g2 = ((ks << 2) | quad) ^ (cl & 7);
      bf16x8 af[4], bb[NW];
#pragma unroll
      for (int i = 0; i < 4; i++)
        af[i] = *(const bf16x8*)&smA[(wm * 64 + i * 16 + cl) * 64 + g2 * 8];
#pragma unroll
      for (int i = 0; i < NW; i++)
        bb[i] = *(const bf16x8*)&smB[(wn * (TN / 2) + i * 16 + cl) * 64 + g2 * 8];
#pragma unroll
      for (int mi = 0; mi < 4; mi++)
#pragma unroll
        for (int ni = 0; ni < NW; ni++)
          acc[mi][ni] = mfma16(af[mi], bb[ni], acc[mi][ni]);
    }
  }
#pragma unroll
  for (int mi = 0; mi < 4; mi++) {
    int row = m0 + wm * 64 + mi * 16 + quad * 4;
#pragma unroll
    for (int ni = 0; ni < NW; ni++) {
      int col = n0 + wn * (TN / 2) + ni * 16 + cl;
#pragma unroll
      for (int r = 0; r < 4; r++) {
        float v = acc[mi][ni][r] + (brow ? bi[row + r] : bi[col]);
        if constexpr (sizeof(OT) == 2) Cb[(long)(row + r) * ldc + col] = f2b(v);
        else Cb[(long)(row + r) * ldc + col] = v;
      }
    }
  }
}

// merged Q/K/V projections: 24 z-slices x 32 xy-tiles = 768 blocks (3/CU)
__global__ __launch_bounds__(256, 2) void gemm_qkv(const u16* __restrict__ xT, const u16* __restrict__ cT,
                                                   const u16* __restrict__ Wb,
                                                   u16* __restrict__ Qb, u16* __restrict__ Kb, u16* __restrict__ Vb,
                                                   const float* __restrict__ bq, const float* __restrict__ bk,
                                                   const float* __restrict__ bv) {
  __shared__ u16 smA[128 * 64], smB[128 * 64];
  const long TCH = (long)T * CH;
  int z = blockIdx.z, sec = z >> 3, zz = z & 7, bx = blockIdx.x;
  const u16 *Ab, *Bb; u16* Cb; const float* bi;
  int m0, n0, ldc; bool brow;
  if (sec == 0) {        // Q = xT * Wq^T -> [B][T][CH]
    Ab = xT + zz * TCH; Bb = Wb;           Cb = Qb + zz * TCH;        bi = bq;
    m0 = (bx >> 2) * 128; n0 = (bx & 3) * 128; ldc = CH; brow = false;
  } else if (sec == 1) { // K = cT * Wk^T -> [B][T][CH]
    Ab = cT + zz * TCH; Bb = Wb + 262144;  Cb = Kb + zz * TCH;        bi = bk;
    m0 = (bx >> 2) * 128; n0 = (bx & 3) * 128; ldc = CH; brow = false;
  } else {               // V = Wv * cT^T -> [B][CH][T]
    Ab = Wb + 2 * 262144; Bb = cT + zz * TCH; Cb = Vb + zz * (long)CH * T; bi = bv;
    m0 = (bx & 3) * 128; n0 = (bx >> 2) * 128; ldc = T; brow = true;
  }
  gemm_core<128, u16>(Ab, CH, Bb, CH, Cb, ldc, bi, brow, m0, n0, CH, smA, smB);
}

// out = Wo * AO^T -> [B][CH][T] fp32.  128x64 tiles -> 512 blocks (2/CU)
__global__ __launch_bounds__(256, 2) void gemm_o(const u16* __restrict__ Wo, const u16* __restrict__ AO,
                                                 float* __restrict__ out, const float* __restrict__ bo) {
  __shared__ u16 smA[128 * 64], smB[64 * 64];
  int z = blockIdx.z;
  gemm_core<64, float>(Wo, CH, AO + z * (long)T * CH, CH, out + z * (long)CH * T, T,
                       bo, true, blockIdx.y * 128, blockIdx.x * 64, CH, smA, smB);
}

// ---- banded attention, raw-exp softmax, XCD-swizzled, reg-prefetched ----
// Q,K: [B][T][CH] bf16; V: [B][CH][T] bf16; AO: [B][T][CH] bf16.
__global__ __launch_bounds__(256, 4) void attn(const u16* __restrict__ Q, const u16* __restrict__ Kt,
                                               const u16* __restrict__ V, u16* __restrict__ AO) {
  __shared__ u16 pb[4][16][40];
  int lane = threadIdx.x & 63, wave = threadIdx.x >> 6;
  int cl = lane & 15, quad = lane >> 4;
  // XCD swizzle: blocks land on XCD (blockIdx.x & 7) round-robin; keep all 16
  // q-tiles of one (b,h) on one XCD -> its 3 MB Q/K/V set stays in that L2.
  int bx = blockIdx.x;
  int xcd = bx & 7, ii = bx >> 3;
  int bh = xcd * 8 + (ii & 7);
  int qt = ii >> 3;
  int b = bh >> 3, h = bh & 7;
  int tq0 = qt * 64 + wave * 16;
  const u16* qb = Q + ((long)(b * T + tq0 + cl) * CH) + h * HD;
  bf16x8 qf0 = *(const bf16x8*)(qb + quad * 8);
  bf16x8 qf1 = *(const bf16x8*)(qb + 32 + quad * 8);
  f32x4 acc[4] = {};
  float lr[4] = {0.f, 0.f, 0.f, 0.f};
  float fir[4];
#pragma unroll
  for (int r = 0; r < 4; r++) fir[r] = (float)(tq0 + quad * 4 + r);
  int s_lo = tq0 - BAND; if (s_lo < 0) s_lo = 0; s_lo &= ~31;
  int s_hi = tq0 + 16 + BAND; if (s_hi > T) s_hi = T;

  // K rows interleaved (lane cl: rows j0+2cl, j0+2cl+1) for packed P writes.
  const u16* kbase = Kt + ((long)(b * T + 2 * cl) * CH) + h * HD + quad * 8;
  const u16* vbase = V + ((long)(b * CH + h * HD + cl) * T) + quad * 8;
  bf16x8 kp[4], vp[4];
#define LOADK(j0, kk)                                                    \
  { const u16* kb = kbase + (long)(j0) * CH;                             \
    kk[0] = *(const bf16x8*)(kb);        kk[1] = *(const bf16x8*)(kb + 32); \
    kk[2] = *(const bf16x8*)(kb + CH);   kk[3] = *(const bf16x8*)(kb + CH + 32); }
#define LOADV(j0, vv)                                                    \
  { const u16* vb = vbase + (j0);                                        \
    vv[0] = *(const bf16x8*)(vb);              vv[1] = *(const bf16x8*)(vb + 16 * T); \
    vv[2] = *(const bf16x8*)(vb + 32 * T);     vv[3] = *(const bf16x8*)(vb + 48 * T); }
  LOADK(s_lo, kp); LOADV(s_lo, vp);

  float je = (float)(s_lo + 2 * cl);
  for (int j0 = s_lo; j0 < s_hi; j0 += 32, je += 32.f) {
    bf16x8 kc[4], vc[4];
#pragma unroll
    for (int i = 0; i < 4; i++) { kc[i] = kp[i]; vc[i] = vp[i]; }
    int jn = (j0 + 32 < s_hi) ? j0 + 32 : j0;   // clamped: last prefetch redundant, in-bounds
    LOADK(jn, kp); LOADV(jn, vp);
    f32x4 z = {0.f, 0.f, 0.f, 0.f};
    f32x4 s0 = mfma16(qf1, kc[1], mfma16(qf0, kc[0], z));  // P cols j0+2n
    f32x4 s1 = mfma16(qf1, kc[3], mfma16(qf0, kc[2], z));  // P cols j0+2n+1
#pragma unroll
    for (int r = 0; r < 4; r++) {
      float de = fabsf(fir[r] - je);
      float dd = fabsf(fir[r] - je - 1.f);
      // p = exp(qk/8)/(1+d) == exp(qk/8 - log1p(d)); softmax shift-invariant.
      constexpr float C2 = 0.125f * 1.4426950408889634f;   // /8, then ln->log2
      float pe = exp2_hw(s0[r] * C2) * __builtin_amdgcn_rcpf(1.f + de);
      float po = exp2_hw(s1[r] * C2) * __builtin_amdgcn_rcpf(1.f + dd);
      pe = (de <= 256.f) ? pe : 0.f;     // out-of-band -> exact 0 (matches ref underflow)
      po = (dd <= 256.f) ? po : 0.f;
      lr[r] += pe + po;
      uint32_t ue, uo;
      { union { float f; uint32_t u; } cv; cv.f = pe; ue = cv.u; cv.f = po; uo = cv.u; }
      uint32_t pk = ((uo + 0x8000u) & 0xffff0000u) | ((ue + 0x8000u) >> 16);
      *(uint32_t*)&pb[wave][quad * 4 + r][2 * cl] = pk;
    }
    bf16x8 pf = *(bf16x8*)&pb[wave][cl][quad * 8];   // A-layout, wave-local
#pragma unroll
    for (int dg = 0; dg < 4; dg++)
      acc[dg] = mfma16(pf, vc[dg], acc[dg]);
  }
#undef LOADK
#undef LOADV
  float inv[4];
#pragma unroll
  for (int r = 0; r < 4; r++) {
    float s = lr[r];
    s += __shfl_xor(s, 1); s += __shfl_xor(s, 2);
    s += __shfl_xor(s, 4); s += __shfl_xor(s, 8);
    inv[r] = __builtin_amdgcn_rcpf(s);
  }
#pragma unroll
  for (int dg = 0; dg < 4; dg++)
#pragma unroll
    for (int r = 0; r < 4; r++)
      AO[((long)(b * T + tq0 + quad * 4 + r) * CH) + h * HD + dg * 16 + cl] = f2b(acc[dg][r] * inv[r]);
}

extern "C" void kernel_launch(void* const* d_in, const int* in_sizes, int n_in,
                              void* d_out, int out_size, void* d_ws, size_t ws_size,
                              hipStream_t stream) {
  const float* x  = (const float*)d_in[0];
  const float* c  = (const float*)d_in[1];
  // d_in[2] = attn_mask: constant all-ones -> identity, skipped
  const float* Wq = (const float*)d_in[3];
  const float* bq = (const float*)d_in[4];
  const float* Wk = (const float*)d_in[5];
  const float* bk = (const float*)d_in[6];
  const float* Wv = (const float*)d_in[7];
  const float* bv = (const float*)d_in[8];
  const float* Wo = (const float*)d_in[9];
  const float* bo = (const float*)d_in[10];
  float* out = (float*)d_out;

  const long NT = (long)B_ * T * CH;
  u16* Wb = (u16*)d_ws;               // 4 x 512x512 bf16
  u16* xT = Wb + 4 * 262144;
  u16* cT = xT + NT;
  u16* Qb = cT + NT;
  u16* Kb = Qb + NT;
  u16* Vb = Kb + NT;
  u16* AO = xT;                       // xT dead after QKV-GEMM; reuse

  cvt_w<<<dim3(512), dim3(256), 0, stream>>>(Wq, Wk, Wv, Wo, Wb);
  tr_cvt<<<dim3(32, 16, 16), dim3(256), 0, stream>>>(x, c, xT, cT);
  gemm_qkv<<<dim3(32, 1, 24), dim3(256), 0, stream>>>(xT, cT, Wb, Qb, Kb, Vb, bq, bk, bv);
  attn<<<dim3(1024), dim3(256), 0, stream>>>(Qb, Kb, Vb, AO);
  gemm_o<<<dim3(16, 4, 8), dim3(256), 0, stream>>>(Wb + 3 * 262144, AO, out, bo);
}

// Round 5
// 153.087 us; speedup vs baseline: 1.5398x; 1.2350x over previous
//
#include <hip/hip_runtime.h>
#include <stdint.h>

typedef unsigned short u16;
typedef __attribute__((ext_vector_type(8))) __bf16 bf16x8;
typedef __attribute__((ext_vector_type(4))) float f32x4;

constexpr int B_ = 8, CH = 512, T = 1024, NH = 8, HD = 64, BAND = 256;

__device__ inline u16 f2b(float f) {
  union { float f; uint32_t u; } v; v.f = f;
  uint32_t r = (v.u + 0x7fffu + ((v.u >> 16) & 1u)) >> 16;
  return (u16)r;
}

__device__ inline f32x4 mfma16(bf16x8 a, bf16x8 b, f32x4 c) {
  return __builtin_amdgcn_mfma_f32_16x16x32_bf16(a, b, c, 0, 0, 0);
}

__device__ __forceinline__ void gld16(const void* g, void* l) {
  __builtin_amdgcn_global_load_lds((__attribute__((address_space(1))) void*)(g),
                                   (__attribute__((address_space(3))) void*)(l),
                                   16, 0, 0);
}

// 2^x via v_exp_f32 (NOT __exp2f: glibc math.h macro clash on this toolchain)
__device__ __forceinline__ float exp2_hw(float x) { return __builtin_amdgcn_exp2f(x); }

// ---- weights fp32 -> bf16, 4x [512][512] row-major ----
__global__ __launch_bounds__(256) void cvt_w(const float* __restrict__ wq, const float* __restrict__ wk,
                                             const float* __restrict__ wv, const float* __restrict__ wo,
                                             u16* __restrict__ out) {
  int idx = blockIdx.x * 256 + threadIdx.x;
  int w = idx >> 15;
  const float* src = (w == 0) ? wq : (w == 1) ? wk : (w == 2) ? wv : wo;
  int e = (idx & 32767) * 8;
  f32x4 a = *(const f32x4*)(src + e);
  f32x4 b = *(const f32x4*)(src + e + 4);
  union { u16 h[8]; bf16x8 v; } r;
  r.h[0] = f2b(a[0]); r.h[1] = f2b(a[1]); r.h[2] = f2b(a[2]); r.h[3] = f2b(a[3]);
  r.h[4] = f2b(b[0]); r.h[5] = f2b(b[1]); r.h[6] = f2b(b[2]); r.h[7] = f2b(b[3]);
  *(bf16x8*)(out + (w << 18) + e) = r.v;
}

// ---- x,c [B][CH][T] fp32 -> xT,cT [B][T][CH] bf16 ----
__global__ __launch_bounds__(256) void tr_cvt(const float* __restrict__ x, const float* __restrict__ c,
                                              u16* __restrict__ xT, u16* __restrict__ cT) {
  __shared__ float tile[32][33];
  int z = blockIdx.z;
  const float* src = (z < B_) ? x : c;
  u16* dst = (z < B_) ? xT : cT;
  int b = (z < B_) ? z : z - B_;
  int t0 = blockIdx.x * 32, c0 = blockIdx.y * 32;
  int tx = threadIdx.x & 31, ty = threadIdx.x >> 5;
#pragma unroll
  for (int k = 0; k < 4; k++)
    tile[ty + 8 * k][tx] = src[(long)(b * CH + c0 + ty + 8 * k) * T + t0 + tx];
  __syncthreads();
#pragma unroll
  for (int k = 0; k < 4; k++)
    dst[(long)(b * T + t0 + ty + 8 * k) * CH + c0 + tx] = f2b(tile[tx][ty + 8 * k]);
}

// ---- shared GEMM core: 128 x TN tile, BK=64, 4 waves, gld16 staging ----
template <int TN, typename OT>
__device__ __forceinline__ void gemm_core(const u16* __restrict__ Ab, int lda,
                                          const u16* __restrict__ Bb, int ldb,
                                          OT* __restrict__ Cb, int ldc,
                                          const float* __restrict__ bi, bool brow,
                                          int m0, int n0, int K, u16* smA, u16* smB) {
  int t = threadIdx.x, lane = t & 63, wave = t >> 6;
  int cl = lane & 15, quad = lane >> 4;
  int wm = wave >> 1, wn = wave & 1;
  int rr = t >> 3, gs = t & 7;
  constexpr int NW = TN / 32;
  f32x4 acc[4][NW] = {};
  for (int k0 = 0; k0 < K; k0 += 64) {
    __syncthreads();
#pragma unroll
    for (int j = 0; j < 4; j++) {
      int R = j * 32 + rr;
      int gc = (gs ^ (R & 7)) << 3;
      gld16(Ab + (long)(m0 + R) * lda + k0 + gc, (char*)smA + j * 4096 + wave * 1024);
      if (j < TN / 32)
        gld16(Bb + (long)(n0 + R) * ldb + k0 + gc, (char*)smB + j * 4096 + wave * 1024);
    }
    __syncthreads();
#pragma unroll
    for (int ks = 0; ks < 2; ks++) {
      int g2 = ((ks << 2) | quad) ^ (cl & 7);
      bf16x8 af[4], bb[NW];
#pragma unroll
      for (int i = 0; i < 4; i++)
        af[i] = *(const bf16x8*)&smA[(wm * 64 + i * 16 + cl) * 64 + g2 * 8];
#pragma unroll
      for (int i = 0; i < NW; i++)
        bb[i] = *(const bf16x8*)&smB[(wn * (TN / 2) + i * 16 + cl) * 64 + g2 * 8];
#pragma unroll
      for (int mi = 0; mi < 4; mi++)
#pragma unroll
        for (int ni = 0; ni < NW; ni++)
          acc[mi][ni] = mfma16(af[mi], bb[ni], acc[mi][ni]);
    }
  }
#pragma unroll
  for (int mi = 0; mi < 4; mi++) {
    int row = m0 + wm * 64 + mi * 16 + quad * 4;
#pragma unroll
    for (int ni = 0; ni < NW; ni++) {
      int col = n0 + wn * (TN / 2) + ni * 16 + cl;
#pragma unroll
      for (int r = 0; r < 4; r++) {
        float v = acc[mi][ni][r] + (brow ? bi[row + r] : bi[col]);
        if constexpr (sizeof(OT) == 2) Cb[(long)(row + r) * ldc + col] = f2b(v);
        else Cb[(long)(row + r) * ldc + col] = v;
      }
    }
  }
}

// merged Q/K/V projections: 24 z-slices x 32 xy-tiles = 768 blocks (3/CU)
__global__ __launch_bounds__(256, 3) void gemm_qkv(const u16* __restrict__ xT, const u16* __restrict__ cT,
                                                   const u16* __restrict__ Wb,
                                                   u16* __restrict__ Qb, u16* __restrict__ Kb, u16* __restrict__ Vb,
                                                   const float* __restrict__ bq, const float* __restrict__ bk,
                                                   const float* __restrict__ bv) {
  __shared__ u16 smA[128 * 64], smB[128 * 64];
  const long TCH = (long)T * CH;
  int z = blockIdx.z, sec = z >> 3, zz = z & 7, bx = blockIdx.x;
  const u16 *Ab, *Bb; u16* Cb; const float* bi;
  int m0, n0, ldc; bool brow;
  if (sec == 0) {        // Q = xT * Wq^T -> [B][T][CH]
    Ab = xT + zz * TCH; Bb = Wb;           Cb = Qb + zz * TCH;        bi = bq;
    m0 = (bx >> 2) * 128; n0 = (bx & 3) * 128; ldc = CH; brow = false;
  } else if (sec == 1) { // K = cT * Wk^T -> [B][T][CH]
    Ab = cT + zz * TCH; Bb = Wb + 262144;  Cb = Kb + zz * TCH;        bi = bk;
    m0 = (bx >> 2) * 128; n0 = (bx & 3) * 128; ldc = CH; brow = false;
  } else {               // V = Wv * cT^T -> [B][CH][T]
    Ab = Wb + 2 * 262144; Bb = cT + zz * TCH; Cb = Vb + zz * (long)CH * T; bi = bv;
    m0 = (bx & 3) * 128; n0 = (bx >> 2) * 128; ldc = T; brow = true;
  }
  gemm_core<128, u16>(Ab, CH, Bb, CH, Cb, ldc, bi, brow, m0, n0, CH, smA, smB);
}

// out = Wo * AO^T -> [B][CH][T] fp32.  128x64 tiles -> 512 blocks
__global__ __launch_bounds__(256, 4) void gemm_o(const u16* __restrict__ Wo, const u16* __restrict__ AO,
                                                 float* __restrict__ out, const float* __restrict__ bo) {
  __shared__ u16 smA[128 * 64], smB[64 * 64];
  int z = blockIdx.z;
  gemm_core<64, float>(Wo, CH, AO + z * (long)T * CH, CH, out + z * (long)CH * T, T,
                       bo, true, blockIdx.y * 128, blockIdx.x * 64, CH, smA, smB);
}

// ---- banded attention, LDS-staged K/V shared by 4 waves, double-buffered ----
// Block = 64 q-rows of one (b,h); wave = 16 q-rows. s-tiles of 64, all tiles
// 64-aligned and fully inside [0,T). K staged s-PERMUTED (LDS row p*32+sub*16+n
// <-> physical s = p*32+2n+sub) so each lane's two P values are s-adjacent ->
// packed b32 P-writes, while P memory stays physical-s-major for the PV A-read.
// V staged [d][s] (natural). XOR chunk-swizzle (chunk g at pos g^(row&7)) makes
// all b128 fragment reads conflict-clean. One barrier per tile: barrier ->
// issue next tile's gld16 -> compute current (staging hides behind compute).
__global__ __launch_bounds__(256, 3) void attn(const u16* __restrict__ Q, const u16* __restrict__ Kt,
                                               const u16* __restrict__ V, u16* __restrict__ AO) {
  __shared__ u16 sK[2][64 * 64];
  __shared__ u16 sV[2][64 * 64];
  __shared__ u16 sP[4][16 * 72];
  int lane = threadIdx.x & 63, wave = threadIdx.x >> 6;
  int cl = lane & 15, quad = lane >> 4;
  // XCD swizzle: all 16 q-tiles of one (b,h) on one XCD (R4: FETCH 72->12 MB).
  int bx = blockIdx.x;
  int xcd = bx & 7, ii = bx >> 3;
  int bh = xcd * 8 + (ii & 7);
  int qt = ii >> 3;
  int b = bh >> 3, h = bh & 7;
  int tq0 = qt * 64;                      // block q base (64-aligned)
  int tqw = tq0 + wave * 16;              // wave q base
  const u16* qb = Q + ((long)(b * T + tqw + cl) * CH) + h * HD;
  bf16x8 qf0 = *(const bf16x8*)(qb + quad * 8);
  bf16x8 qf1 = *(const bf16x8*)(qb + 32 + quad * 8);
  f32x4 acc[4] = {};
  float lr[4] = {0.f, 0.f, 0.f, 0.f};
  float fir[4];
#pragma unroll
  for (int r = 0; r < 4; r++) fir[r] = (float)(tqw + quad * 4 + r);
  int lo = tq0 - BAND; if (lo < 0) lo = 0;            // 64-aligned
  int hi = tq0 + 64 + BAND; if (hi > T) hi = T;       // 64-aligned
  int nt = (hi - lo) >> 6;

  int rl = lane >> 3, cg = lane & 7;                   // staging lane roles
  const u16* ksrc = Kt + (long)b * T * CH + h * HD;
  const u16* vsrc = V + ((long)(b * CH + h * HD) * T);

#define STAGE(buf, j0)                                                          \
  {                                                                             \
    _Pragma("unroll")                                                           \
    for (int i = 0; i < 2; i++) {                                               \
      int r = wave * 16 + i * 8 + rl;                                           \
      int s = ((r >> 5) << 5) + ((r >> 4) & 1) + ((r & 15) << 1);               \
      gld16(ksrc + (long)(j0 + s) * CH + ((cg ^ (r & 7)) << 3),                 \
            (char*)&sK[buf][(wave * 16 + i * 8) * 64]);                         \
      gld16(vsrc + (long)r * T + (j0) + ((cg ^ (r & 7)) << 3),                  \
            (char*)&sV[buf][(wave * 16 + i * 8) * 64]);                         \
    }                                                                           \
  }

  STAGE(0, lo)
  constexpr float C2 = 0.125f * 1.4426950408889634f;   // /8 then ln->log2
  for (int it = 0; it < nt; it++) {
    int cur = it & 1;
    int j0 = lo + it * 64;
    __syncthreads();                 // drains vmcnt: tile `it` staged; prev reads done
    if (it + 1 < nt) STAGE(1 - cur, j0 + 64)
    // ---- QK: 4 col-groups (p,sub), cols s = j0 + p*32 + 2*cl + sub ----
    f32x4 sg[2][2];
#pragma unroll
    for (int p = 0; p < 2; p++)
#pragma unroll
      for (int sub = 0; sub < 2; sub++) {
        const u16* kr = &sK[cur][(p * 32 + sub * 16 + cl) * 64];
        bf16x8 k0 = *(const bf16x8*)&kr[((quad ^ (cl & 7)) << 3)];
        bf16x8 k1 = *(const bf16x8*)&kr[(((4 | quad) ^ (cl & 7)) << 3)];
        f32x4 z = {0.f, 0.f, 0.f, 0.f};
        sg[p][sub] = mfma16(qf1, k1, mfma16(qf0, k0, z));
      }
    // ---- softmax (raw exp; p = exp(qk/8)/(1+d), band-> exact 0) ----
#pragma unroll
    for (int p = 0; p < 2; p++) {
      float jb = (float)(j0 + p * 32 + 2 * cl);
#pragma unroll
      for (int r = 0; r < 4; r++) {
        float de = fabsf(fir[r] - jb);
        float dd = fabsf(fir[r] - jb - 1.f);
        float pe = exp2_hw(sg[p][0][r] * C2) * __builtin_amdgcn_rcpf(1.f + de);
        float po = exp2_hw(sg[p][1][r] * C2) * __builtin_amdgcn_rcpf(1.f + dd);
        pe = (de <= 256.f) ? pe : 0.f;
        po = (dd <= 256.f) ? po : 0.f;
        lr[r] += pe + po;
        uint32_t ue, uo;
        { union { float f; uint32_t u; } cv; cv.f = pe; ue = cv.u; cv.f = po; uo = cv.u; }
        uint32_t pk = ((uo + 0x8000u) & 0xffff0000u) | ((ue + 0x8000u) >> 16);
        *(uint32_t*)&sP[wave][(quad * 4 + r) * 72 + p * 32 + 2 * cl] = pk;
      }
    }
    // ---- PV: A = P (physical-s-major), B = V[d][s] ----
#pragma unroll
    for (int ks = 0; ks < 2; ks++) {
      bf16x8 pf = *(bf16x8*)&sP[wave][cl * 72 + ks * 32 + quad * 8];
#pragma unroll
      for (int dg = 0; dg < 4; dg++) {
        bf16x8 vf = *(const bf16x8*)&sV[cur][(dg * 16 + cl) * 64 +
                                             ((((ks << 2) | quad) ^ (cl & 7)) << 3)];
        acc[dg] = mfma16(pf, vf, acc[dg]);
      }
    }
  }
#undef STAGE
  float inv[4];
#pragma unroll
  for (int r = 0; r < 4; r++) {
    float s = lr[r];
    s += __shfl_xor(s, 1); s += __shfl_xor(s, 2);
    s += __shfl_xor(s, 4); s += __shfl_xor(s, 8);
    inv[r] = __builtin_amdgcn_rcpf(s);
  }
#pragma unroll
  for (int dg = 0; dg < 4; dg++)
#pragma unroll
    for (int r = 0; r < 4; r++)
      AO[((long)(b * T + tqw + quad * 4 + r) * CH) + h * HD + dg * 16 + cl] = f2b(acc[dg][r] * inv[r]);
}

extern "C" void kernel_launch(void* const* d_in, const int* in_sizes, int n_in,
                              void* d_out, int out_size, void* d_ws, size_t ws_size,
                              hipStream_t stream) {
  const float* x  = (const float*)d_in[0];
  const float* c  = (const float*)d_in[1];
  // d_in[2] = attn_mask: constant all-ones -> identity, skipped
  const float* Wq = (const float*)d_in[3];
  const float* bq = (const float*)d_in[4];
  const float* Wk = (const float*)d_in[5];
  const float* bk = (const float*)d_in[6];
  const float* Wv = (const float*)d_in[7];
  const float* bv = (const float*)d_in[8];
  const float* Wo = (const float*)d_in[9];
  const float* bo = (const float*)d_in[10];
  float* out = (float*)d_out;

  const long NT = (long)B_ * T * CH;
  u16* Wb = (u16*)d_ws;               // 4 x 512x512 bf16
  u16* xT = Wb + 4 * 262144;
  u16* cT = xT + NT;
  u16* Qb = cT + NT;
  u16* Kb = Qb + NT;
  u16* Vb = Kb + NT;
  u16* AO = xT;                       // xT dead after QKV-GEMM; reuse

  cvt_w<<<dim3(512), dim3(256), 0, stream>>>(Wq, Wk, Wv, Wo, Wb);
  tr_cvt<<<dim3(32, 16, 16), dim3(256), 0, stream>>>(x, c, xT, cT);
  gemm_qkv<<<dim3(32, 1, 24), dim3(256), 0, stream>>>(xT, cT, Wb, Qb, Kb, Vb, bq, bk, bv);
  attn<<<dim3(1024), dim3(256), 0, stream>>>(Qb, Kb, Vb, AO);
  gemm_o<<<dim3(16, 4, 8), dim3(256), 0, stream>>>(Wb + 3 * 262144, AO, out, bo);
}